// Round 2
// baseline (696.246 us; speedup 1.0000x reference)
//
#include <hip/hip_runtime.h>

constexpr int DIM = 96;
constexpr int HW  = DIM * DIM;            // 9216
constexpr int DHW = DIM * DIM * DIM;      // 884736
constexpr int NC  = 64;

constexpr int TZ = 4, TY = 8, TX = 32;    // spatial tile per block (4 outs/thread in x)
constexpr int LZ = TZ;                    // dz fixed per block -> only TZ z-planes staged
constexpr int LY = TY + 2;                // 10 (y halo)
constexpr int LXP = 36;                   // 34 live x + 2 pad -> 144B rows (16B aligned)
constexpr int LDS_PAD = 1536;             // 6*256 -> branch-free staging (pad = dummy loads)
constexpr int NSTG = LDS_PAD / 256;       // 6 dword loads / thread / channel

constexpr int NXT = DIM / TX;             // 3 x-tiles
constexpr int NYT = DIM / TY;             // 12 y-tiles
constexpr int NZT = DIM / TZ;             // 24 z-tiles
constexpr int NTILE = NXT * NYT * NZT;    // 864 spatial tiles
constexpr int NBLK  = NTILE * 3;          // 2592 blocks

typedef const __attribute__((address_space(1))) unsigned int* gas_ptr;
typedef __attribute__((address_space(3))) unsigned int* las_ptr;

__global__ __launch_bounds__(256, 8)     // VGPR<=64 -> 8 blocks/CU resident
void wincorr_kernel(const float* __restrict__ fixed_,
                    const float* __restrict__ moving,
                    float* __restrict__ out)
{
    __shared__ __align__(16) float sm[2][LDS_PAD];   // 12 KB double buffer

    const int tid = threadIdx.x;
    const int tx = tid & 7;          // 8 x-chunks of 4
    const int ty = (tid >> 3) & 7;   // 8 y
    const int tz = tid >> 6;         // 4 z (wave id)

    // XCD-aware decode: HW round-robins linear block id across 8 XCDs (id%8).
    // Group of 24 ids = 8 spatially-contiguous tiles x 3 dz, arranged so the
    // 3 dz-siblings of a tile have ids {s, s+8, s+16} within the group ->
    // same XCD -> moving slab + fixed stream dedup'd in that XCD's L2.
    const int n  = blockIdx.x;
    const int g  = n / 24;
    const int p  = n - g * 24;
    const int s  = p & 7;            // XCD slot
    const int dz = p >> 3;           // 0..2
    const int tile = g * 8 + s;      // 0..863, x fastest -> neighbors share halos
    const int xt = tile % NXT;
    const int yt = (tile / NXT) % NYT;
    const int zt = tile / (NXT * NYT);
    const int bx0 = xt * TX;
    const int by0 = yt * TY;
    const int bz0 = zt * TZ;

    // Channel-invariant staging source offsets (edge clamp here).
    int g_off[NSTG];
#pragma unroll
    for (int i = 0; i < NSTG; ++i) {
        const int t  = tid + i * 256;
        const int lz = t / (LY * LXP);
        const int r  = t - lz * (LY * LXP);
        const int ly = r / LXP;
        const int lx = r - ly * LXP;            // lx 34,35 = pad -> dummy (clamped, never read)
        const int gz = min(max(bz0 + dz - 1 + lz, 0), DIM - 1);
        const int gy = min(max(by0 - 1 + ly, 0), DIM - 1);
        const int gx = min(max(bx0 - 1 + lx, 0), DIM - 1);
        g_off[i] = gz * HW + gy * DIM + gx;
    }

    const int z = bz0 + tz, y = by0 + ty, x0 = bx0 + 4 * tx;
    const int foff = z * HW + y * DIM + x0;

    float acc[9][4];
#pragma unroll
    for (int k = 0; k < 9; ++k)
#pragma unroll
        for (int j = 0; j < 4; ++j) acc[k][j] = 0.f;

    // Prologue: async-stage channel 0 into buffer 0, prefetch fixed ch0
#pragma unroll
    for (int i = 0; i < NSTG; ++i)
        __builtin_amdgcn_global_load_lds((gas_ptr)(moving + g_off[i]),
                                         (las_ptr)&sm[0][tid + i * 256], 4, 0, 0);
    float4 pf = *(const float4*)(fixed_ + foff);
    __syncthreads();                             // vmcnt(0) drain -> buf0 ready

    const int rbase = (tz * LY + ty) * LXP + 4 * tx;

    for (int c = 0; c < NC; ++c) {
        const int cur = c & 1;

        // Issue next channel's staging first: HW DMA overlaps the compute below,
        // drained by the single barrier at loop end.
        if (c + 1 < NC) {
            const float* mc = moving + (size_t)(c + 1) * DHW;
            float* dst = sm[cur ^ 1];
#pragma unroll
            for (int i = 0; i < NSTG; ++i)
                __builtin_amdgcn_global_load_lds((gas_ptr)(mc + g_off[i]),
                                                 (las_ptr)&dst[tid + i * 256], 4, 0, 0);
        }
        const float4 fv = pf;
        if (c + 1 < NC)
            pf = *(const float4*)(fixed_ + (size_t)(c + 1) * DHW + foff);

        const float* buf = sm[cur];
#pragma unroll
        for (int dy = 0; dy < 3; ++dy) {
            const float* row = buf + rbase + dy * LXP;   // 16B aligned
            const float4 w0 = *(const float4*)row;
            const float2 w1 = *(const float2*)(row + 4);
            const float w[6] = {w0.x, w0.y, w0.z, w0.w, w1.x, w1.y};
            const int kb = dy * 3;
#pragma unroll
            for (int dx = 0; dx < 3; ++dx) {
                acc[kb + dx][0] += fv.x * w[dx + 0];
                acc[kb + dx][1] += fv.y * w[dx + 1];
                acc[kb + dx][2] += fv.z * w[dx + 2];
                acc[kb + dx][3] += fv.w * w[dx + 3];
            }
        }
        __syncthreads();   // one barrier/channel: reads of buf done, next buf landed
    }

    // Epilogue: this block owns taps dz*9 .. dz*9+8; scale 64^-0.5 = 0.125
#pragma unroll
    for (int k = 0; k < 9; ++k) {
        float4 o;
        o.x = acc[k][0] * 0.125f;
        o.y = acc[k][1] * 0.125f;
        o.z = acc[k][2] * 0.125f;
        o.w = acc[k][3] * 0.125f;
        *(float4*)(out + (size_t)(dz * 9 + k) * DHW + foff) = o;
    }
}

extern "C" void kernel_launch(void* const* d_in, const int* in_sizes, int n_in,
                              void* d_out, int out_size, void* d_ws, size_t ws_size,
                              hipStream_t stream) {
    const float* fixed_  = (const float*)d_in[0];
    const float* moving  = (const float*)d_in[1];
    float* out = (float*)d_out;
    dim3 grid(NBLK);                 // 2592 flat; in-kernel XCD-aware decode
    dim3 block(256);
    wincorr_kernel<<<grid, block, 0, stream>>>(fixed_, moving, out);
}

// Round 3
// 597.721 us; speedup vs baseline: 1.1648x; 1.1648x over previous
//
#include <hip/hip_runtime.h>

constexpr int DIM = 96;
constexpr int HW  = DIM * DIM;            // 9216
constexpr int DHW = DIM * DIM * DIM;      // 884736
constexpr int NC  = 64;
constexpr int NK  = 27;

// Tile: 4(z) x 8(y) x 16(x) outputs per block, 2 outputs/thread in x.
// acc[27][2] = 54 floats -> ~80 VGPR -> 6 blocks/CU (75% occupancy cap).
constexpr int TZ = 4, TY = 8, TX = 16;
constexpr int LZ = TZ + 2;                // 6 staged z-planes
constexpr int LY = TY + 2;                // 10
constexpr int LXP = 20;                   // 18 live (16+2 halo) + 2 pad words
constexpr int SLAB = LZ * LY * LXP;       // 1200 words actually read
constexpr int NSTG = 5;                   // 5*256 = 1280 staged (80 dummy, branch-free)
constexpr int LDSN = NSTG * 256;          // 1280

typedef const __attribute__((address_space(1))) unsigned int* gas_ptr;
typedef __attribute__((address_space(3))) unsigned int* las_ptr;

__global__ __launch_bounds__(256, 6)      // cap ~85 VGPR -> 6 waves/SIMD
void wincorr_kernel(const float* __restrict__ fixed_,
                    const float* __restrict__ moving,
                    float* __restrict__ out)
{
    __shared__ __align__(16) float sm[2][LDSN];   // 10.25 KB double buffer

    const int tid = threadIdx.x;
    const int tx = tid & 7;          // 8 x-chunks of 2
    const int ty = (tid >> 3) & 7;   // 8 y
    const int tz = tid >> 6;         // 4 z (wave id)
    const int bx0 = blockIdx.x * TX;
    const int by0 = blockIdx.y * TY;
    const int bz0 = blockIdx.z * TZ;

    // Channel-invariant staging source offsets (edge clamp here).
    // LDS layout is forced linear (global_load_lds dest = wave base + lane*4):
    // t -> (lz, ly, lx) with row stride LXP; lx 18,19 and t>=1200 are dummies.
    int g_off[NSTG];
#pragma unroll
    for (int i = 0; i < NSTG; ++i) {
        const int t  = tid + i * 256;
        const int lz = t / (LY * LXP);               // 0..6 (6 = dummy tail)
        const int r  = t - lz * (LY * LXP);
        const int ly = r / LXP;
        const int lx = r - ly * LXP;
        const int gz = min(max(bz0 - 1 + lz, 0), DIM - 1);
        const int gy = min(max(by0 - 1 + ly, 0), DIM - 1);
        const int gx = min(max(bx0 - 1 + lx, 0), DIM - 1);
        g_off[i] = gz * HW + gy * DIM + gx;
    }

    const int z = bz0 + tz, y = by0 + ty, x0 = bx0 + 2 * tx;
    const int foff = z * HW + y * DIM + x0;

    float acc[NK][2];
#pragma unroll
    for (int k = 0; k < NK; ++k) { acc[k][0] = 0.f; acc[k][1] = 0.f; }

    // Prologue: async-stage channel 0, prefetch fixed ch0
#pragma unroll
    for (int i = 0; i < NSTG; ++i)
        __builtin_amdgcn_global_load_lds((gas_ptr)(moving + g_off[i]),
                                         (las_ptr)&sm[0][tid + i * 256], 4, 0, 0);
    float2 pf = *(const float2*)(fixed_ + foff);
    __syncthreads();                                  // vmcnt(0) drain -> buf0 ready

    const int rb = 2 * tx;                            // even word -> 8B-aligned reads

    for (int c = 0; c < NC; ++c) {
        const int cur = c & 1;

        // Issue next channel's DMA first; it flies during the compute below and
        // is drained by the single barrier at loop end.
        if (c + 1 < NC) {
            const float* mc = moving + (size_t)(c + 1) * DHW;
            float* dst = sm[cur ^ 1];
#pragma unroll
            for (int i = 0; i < NSTG; ++i)
                __builtin_amdgcn_global_load_lds((gas_ptr)(mc + g_off[i]),
                                                 (las_ptr)&dst[tid + i * 256], 4, 0, 0);
        }
        const float2 fv = pf;
        if (c + 1 < NC)
            pf = *(const float2*)(fixed_ + (size_t)(c + 1) * DHW + foff);

        const float* buf = sm[cur];
#pragma unroll
        for (int dz = 0; dz < 3; ++dz)
#pragma unroll
        for (int dy = 0; dy < 3; ++dy) {
            const float* row = buf + ((tz + dz) * LY + (ty + dy)) * LXP + rb;
            const float2 a = *(const float2*)row;        // words 2tx,2tx+1
            const float2 b = *(const float2*)(row + 2);  // words 2tx+2,2tx+3
            const int kb = (dz * 3 + dy) * 3;
            acc[kb + 0][0] += fv.x * a.x;  acc[kb + 0][1] += fv.y * a.y;
            acc[kb + 1][0] += fv.x * a.y;  acc[kb + 1][1] += fv.y * b.x;
            acc[kb + 2][0] += fv.x * b.x;  acc[kb + 2][1] += fv.y * b.y;
        }
        __syncthreads();   // reads of buf done + next buf landed (one barrier/channel)
    }

    // Epilogue: scale by 64^-0.5 = 0.125, 8B coalesced stores
#pragma unroll
    for (int k = 0; k < NK; ++k) {
        float2 o;
        o.x = acc[k][0] * 0.125f;
        o.y = acc[k][1] * 0.125f;
        *(float2*)(out + (size_t)k * DHW + foff) = o;
    }
}

extern "C" void kernel_launch(void* const* d_in, const int* in_sizes, int n_in,
                              void* d_out, int out_size, void* d_ws, size_t ws_size,
                              hipStream_t stream) {
    const float* fixed_  = (const float*)d_in[0];
    const float* moving  = (const float*)d_in[1];
    float* out = (float*)d_out;
    dim3 grid(DIM / TX, DIM / TY, DIM / TZ);   // 6 x 12 x 24 = 1728 blocks, plain 3D
    dim3 block(256);
    wincorr_kernel<<<grid, block, 0, stream>>>(fixed_, moving, out);
}